// Round 6
// baseline (193.344 us; speedup 1.0000x reference)
//
#include <hip/hip_runtime.h>
#include <hip/hip_bf16.h>

// 32 graphs x 128 nodes, F=64, HID=128, OUT=64
#define F_IN 64
#define HID 128
#define OUTF 64
#define NN 128
#define NB 32
#define TOTAL 4096

#define NEG_LOG2E (-1.4426950408889634f)
#define NEG_LN2 (-0.6931471805599453f)

typedef short bf16x8 __attribute__((ext_vector_type(8)));
typedef float f32x4 __attribute__((ext_vector_type(4)));

static __device__ __forceinline__ short f2bf(float v) {
  __hip_bfloat16 h = __float2bfloat16(v);
  return __builtin_bit_cast(short, h);
}

static __device__ __forceinline__ float fexp2(float x) {
#if __has_builtin(__builtin_amdgcn_exp2f)
  return __builtin_amdgcn_exp2f(x);  // v_exp_f32: natively 2^x
#else
  return exp2f(x);
#endif
}

// ---------------------------------------------------------------------------
// uv_prep: 256 blocks x 256 thr; block handles 16 nodes.
//   uvp[n][c] = -log2e * (h[n]@Wcat[:,c] + (c>=128 ? b1[c-128] : 0))
// Blocks 0-63 emit w2t bf16 [c][k] (plain W2^T). Block 64 emits
// w0p = -log2e*W1[0,:] and b2p = -log2e*b2.
// ---------------------------------------------------------------------------
__global__ __launch_bounds__(256) void uv_prep(
    const float* __restrict__ feat,
    const float* __restrict__ W1,
    const float* __restrict__ W2,
    const float* __restrict__ b1,
    const float* __restrict__ b2,
    float* __restrict__ uvp,
    __hip_bfloat16* __restrict__ w2t,
    float* __restrict__ w0p,
    float* __restrict__ b2p) {
  __shared__ __align__(16) char wcat[256 * 128];  // 256 cols x 64 k bf16
  const int tid = threadIdx.x;
  {
    const int c = tid;
    const int cc = c & 127;
    const int rbase = (c < HID) ? 1 : 65;
#pragma unroll
    for (int p = 0; p < 8; ++p) {
      bf16x8 pk;
#pragma unroll
      for (int m = 0; m < 8; ++m)
        pk[m] = f2bf(W1[(rbase + p * 8 + m) * HID + cc]);
      *reinterpret_cast<bf16x8*>(wcat + c * 128 + ((p ^ (c & 7)) << 4)) = pk;
    }
  }
  if (blockIdx.x < 64) {
    const int e = blockIdx.x * 256 + tid;  // 0..16383
    const int kk = e >> 7, cc2 = e & 127;
    w2t[cc2 * HID + kk] = __float2bfloat16(W2[kk * HID + cc2]);
  } else if (blockIdx.x == 64) {
    if (tid < HID) w0p[tid] = NEG_LOG2E * W1[tid];
    else b2p[tid - HID] = NEG_LOG2E * b2[tid - HID];
  }
  __syncthreads();

  const int wave = tid >> 6, lane = tid & 63;
  const int lr = lane & 15, kg = lane >> 4;
  const int r0 = blockIdx.x * 16;

  f32x4 acc[4];
#pragma unroll
  for (int ct = 0; ct < 4; ++ct) acc[ct] = {0.f, 0.f, 0.f, 0.f};

#pragma unroll
  for (int ks = 0; ks < 2; ++ks) {
    const float* fp = feat + (size_t)(r0 + lr) * F_IN + ks * 32 + kg * 8;
    const f32x4 fa = *reinterpret_cast<const f32x4*>(fp);
    const f32x4 fb = *reinterpret_cast<const f32x4*>(fp + 4);
    bf16x8 a;
#pragma unroll
    for (int m = 0; m < 4; ++m) {
      a[m] = f2bf(fa[m]);
      a[4 + m] = f2bf(fb[m]);
    }
    const int slot = ks * 4 + kg;
#pragma unroll
    for (int ct = 0; ct < 4; ++ct) {
      const int c = wave * 64 + ct * 16 + lr;
      const bf16x8 w = *reinterpret_cast<const bf16x8*>(
          wcat + c * 128 + ((slot ^ (c & 7)) << 4));
      acc[ct] = __builtin_amdgcn_mfma_f32_16x16x32_bf16(a, w, acc[ct], 0, 0, 0);
    }
  }
#pragma unroll
  for (int ct = 0; ct < 4; ++ct) {
    const int c = wave * 64 + ct * 16 + lr;
    const float badd = (c >= HID) ? b1[c - HID] : 0.f;
#pragma unroll
    for (int reg = 0; reg < 4; ++reg) {
      const int r = r0 + kg * 4 + reg;
      uvp[(size_t)r * 256 + c] = NEG_LOG2E * (acc[ct][reg] + badd);
    }
  }
}

// ---------------------------------------------------------------------------
// main: 1024 blocks x 256 thr (4 waves). Wave owns one i: 128 pairs, 8 chunks
// of 16. Swapped MFMA: acc[ch,pair] = W2^T-frag (A) x z1-frag (B).
// No LDS, no barriers. W2 cht0-3 register-resident, cht4-7 reloaded (L1).
// All values pre-scaled by -log2e: exp2 with zero multiplies; acc = -log2e*z2.
// ---------------------------------------------------------------------------
__global__ __launch_bounds__(256, 2) void sake_main(
    const float* __restrict__ coord,
    const float* __restrict__ w0p,
    const float* __restrict__ b2p,
    const float* __restrict__ uvp,
    const __hip_bfloat16* __restrict__ w2t,
    float* __restrict__ part) {
  const int tid = threadIdx.x;
  const int wave = tid >> 6, lane = tid & 63;
  const int lr = lane & 15, kg = lane >> 4;
  // XCD swizzle: 1024 blocks -> 128 contiguous per XCD (4 graphs per XCD)
  const int bid = (blockIdx.x & 7) * 128 + (blockIdx.x >> 3);
  const int gi = bid * 4 + wave;  // 0..4095
  const int b = gi >> 7, i = gi & 127;

  const short* w2s = reinterpret_cast<const short*>(w2t);

  // W2 A-frags for channel-tiles 0..3, register-resident (64 VGPR)
  bf16x8 w2f[4][4];
#pragma unroll
  for (int cht = 0; cht < 4; ++cht)
#pragma unroll
    for (int ks = 0; ks < 4; ++ks)
      w2f[cht][ks] = *reinterpret_cast<const bf16x8*>(
          w2s + (cht * 16 + lr) * HID + ks * 32 + kg * 8);

  const float* xi = coord + (size_t)(b * NN + i) * 3;
  const float xix = xi[0], xiy = xi[1], xiz = xi[2];
  const float* vrow = uvp + ((size_t)b * NN + i) * 256 + HID;  // v'' (k-slice)
  const float* ubase = uvp + (size_t)b * NN * 256;

  f32x4 csum[8];
#pragma unroll
  for (int c = 0; c < 8; ++c) csum[c] = {0.f, 0.f, 0.f, 0.f};

#pragma unroll 2
  for (int ch = 0; ch < 8; ++ch) {
    const int j = ch * 16 + lr;  // this lane's pair (B-col = lr)

    // W2 A-frags cht 4..7 (transient 64 VGPR; L1-hot after chunk 0) —
    // issued early so latency hides under the silu burst below.
    bf16x8 wl[4][4];
#pragma unroll
    for (int c4 = 0; c4 < 4; ++c4)
#pragma unroll
      for (int ks = 0; ks < 4; ++ks)
        wl[c4][ks] = *reinterpret_cast<const bf16x8*>(
            w2s + ((4 + c4) * 16 + lr) * HID + ks * 32 + kg * 8);

    // d2 (exact f32)
    const float* xj = coord + (size_t)(b * NN + j) * 3;
    const float dx = xj[0] - xix, dy = xj[1] - xiy, dz = xj[2] - xiz;
    const float d2 = dx * dx + dy * dy + dz * dz;

    // z1' = -log2e*z1 ; s = z1'*rcp(1+2^z1') = -log2e*silu(z1)
    const float* urow = ubase + (size_t)j * 256;
    bf16x8 zb[4];
#pragma unroll
    for (int ks = 0; ks < 4; ++ks) {
      const int c0 = ks * 32 + kg * 8;
      const f32x4 ua = *reinterpret_cast<const f32x4*>(urow + c0);
      const f32x4 ub = *reinterpret_cast<const f32x4*>(urow + c0 + 4);
      const f32x4 va = *reinterpret_cast<const f32x4*>(vrow + c0);
      const f32x4 vb = *reinterpret_cast<const f32x4*>(vrow + c0 + 4);
      const f32x4 wa = *reinterpret_cast<const f32x4*>(w0p + c0);
      const f32x4 wb = *reinterpret_cast<const f32x4*>(w0p + c0 + 4);
#pragma unroll
      for (int m = 0; m < 4; ++m) {
        const float z = fmaf(d2, wa[m], ua[m] + va[m]);
        const float s = z * __builtin_amdgcn_rcpf(1.f + fexp2(z));
        zb[ks][m] = f2bf(s);
      }
#pragma unroll
      for (int m = 0; m < 4; ++m) {
        const float z = fmaf(d2, wb[m], ub[m] + vb[m]);
        const float s = z * __builtin_amdgcn_rcpf(1.f + fexp2(z));
        zb[ks][4 + m] = f2bf(s);
      }
    }

    // acc init = b2' (L1-hot f32x4 loads), then 32 MFMAs
    f32x4 acc[8];
#pragma unroll
    for (int c = 0; c < 8; ++c)
      acc[c] = *reinterpret_cast<const f32x4*>(b2p + c * 16 + kg * 4);

#pragma unroll
    for (int ks = 0; ks < 4; ++ks) {
#pragma unroll
      for (int c = 0; c < 4; ++c)
        acc[c] = __builtin_amdgcn_mfma_f32_16x16x32_bf16(w2f[c][ks], zb[ks],
                                                         acc[c], 0, 0, 0);
#pragma unroll
      for (int c = 0; c < 4; ++c)
        acc[4 + c] = __builtin_amdgcn_mfma_f32_16x16x32_bf16(wl[c][ks], zb[ks],
                                                             acc[4 + c], 0, 0, 0);
    }

    // z2 epilogue: acc = -log2e*z2 ; csum += acc * rcp(1+2^acc)
#pragma unroll
    for (int c = 0; c < 8; ++c)
#pragma unroll
      for (int m = 0; m < 4; ++m) {
        const float z = acc[c][m];
        const float y = __builtin_amdgcn_rcpf(1.f + fexp2(z));
        csum[c][m] = fmaf(z, y, csum[c][m]);
      }
  }

  // reduce csum over the 16-lane lr group (pairs), then lane lr==0 writes
#pragma unroll
  for (int c = 0; c < 8; ++c)
#pragma unroll
    for (int m = 0; m < 4; ++m) {
      float s = csum[c][m];
      s += __shfl_xor(s, 1);
      s += __shfl_xor(s, 2);
      s += __shfl_xor(s, 4);
      s += __shfl_xor(s, 8);
      csum[c][m] = s;
    }
  if (lr == 0) {
    float* dst = part + (size_t)gi * HID;
#pragma unroll
    for (int c = 0; c < 8; ++c)
      *reinterpret_cast<f32x4*>(dst + c * 16 + kg * 4) = csum[c];
  }
}

// ---------------------------------------------------------------------------
// final: out[b] = -ln2*(sum_i part[b*128+i]) @ W3 + 16384*b3   (f32, exact)
// ---------------------------------------------------------------------------
__global__ void final_kernel(const float* __restrict__ part,
                             const float* __restrict__ W3,
                             const float* __restrict__ b3,
                             float* __restrict__ out) {
  __shared__ float s2[2][HID];
  __shared__ float s[HID];
  int b = blockIdx.x, t = threadIdx.x;
  int c = t & 127, half = t >> 7;
  float a = 0.f;
  for (int g = half * 64; g < half * 64 + 64; ++g)
    a += part[(size_t)(b * NN + g) * HID + c];
  s2[half][c] = a;
  __syncthreads();
  if (t < HID) s[t] = (s2[0][t] + s2[1][t]) * NEG_LN2;  // undo -log2e scale
  __syncthreads();
  if (t < OUTF) {
    float o = 16384.f * b3[t];
    for (int c2 = 0; c2 < HID; ++c2) o += s[c2] * W3[c2 * OUTF + t];
    out[b * OUTF + t] = o;
  }
}

// ---------------------------------------------------------------------------
extern "C" void kernel_launch(void* const* d_in, const int* in_sizes, int n_in,
                              void* d_out, int out_size, void* d_ws, size_t ws_size,
                              hipStream_t stream) {
  const float* feat = (const float*)d_in[0];
  const float* coord = (const float*)d_in[1];
  const float* W1 = (const float*)d_in[2];
  const float* b1 = (const float*)d_in[3];
  const float* W2 = (const float*)d_in[4];
  const float* b2 = (const float*)d_in[5];
  const float* W3 = (const float*)d_in[6];
  const float* b3 = (const float*)d_in[7];
  float* out = (float*)d_out;

  char* ws = (char*)d_ws;
  __hip_bfloat16* w2t = (__hip_bfloat16*)ws;              // 32 KB (W2^T bf16 [c][k])
  float* w0p = (float*)(ws + 32 * 1024);                  // 512 B
  float* b2p = (float*)(ws + 36 * 1024);                  // 512 B
  float* uvp = (float*)(ws + 64 * 1024);                  // 4 MB
  float* part = (float*)(ws + 64 * 1024 + 4096 * 1024);   // 2 MB (4096 x 128)

  uv_prep<<<256, 256, 0, stream>>>(feat, W1, W2, b1, b2, uvp, w2t, w0p, b2p);
  sake_main<<<1024, 256, 0, stream>>>(coord, w0p, b2p, uvp, w2t, part);
  final_kernel<<<NB, 256, 0, stream>>>(part, W3, b3, out);
}

// Round 7
// 60.485 us; speedup vs baseline: 3.1966x; 3.1966x over previous
//
#include <hip/hip_runtime.h>
#include <hip/hip_bf16.h>

// 32 graphs x 128 nodes, F=64, HID=128, OUT=64
#define F_IN 64
#define HID 128
#define OUTF 64
#define NN 128
#define NB 32
#define TOTAL 4096

#define NEG_LOG2E (-1.4426950408889634f)
#define NEG_LN2 (-0.6931471805599453f)

typedef short bf16x8 __attribute__((ext_vector_type(8)));
typedef float f32x4 __attribute__((ext_vector_type(4)));

static __device__ __forceinline__ short f2bf(float v) {
  __hip_bfloat16 h = __float2bfloat16(v);
  return __builtin_bit_cast(short, h);
}

static __device__ __forceinline__ float fexp2(float x) {
#if __has_builtin(__builtin_amdgcn_exp2f)
  return __builtin_amdgcn_exp2f(x);  // v_exp_f32 is natively 2^x
#else
  return exp2f(x);
#endif
}

// ---------------------------------------------------------------------------
// uv_prep: 256 blocks x 256 thr; block handles 16 nodes.
//   uvp[n][c] = -log2e * (h[n]@Wcat[:,c] + (c>=128 ? b1[c-128] : 0))
// Blocks 0-63 emit PRE-SWIZZLED bf16 W2^T (w2swz): row c (256B), 16B slot
// (k>>3)^(c&7), intra-slot (k&7)*2. Block 64 emits w0p=-log2e*W1[0,:],
// b2p=-log2e*b2.
// ---------------------------------------------------------------------------
__global__ __launch_bounds__(256) void uv_prep(
    const float* __restrict__ feat,
    const float* __restrict__ W1,
    const float* __restrict__ W2,
    const float* __restrict__ b1,
    const float* __restrict__ b2,
    float* __restrict__ uvp,
    __hip_bfloat16* __restrict__ w2swz,
    float* __restrict__ w0p,
    float* __restrict__ b2p) {
  __shared__ __align__(16) char wcat[256 * 128];  // 256 cols x 64 k bf16
  const int tid = threadIdx.x;
  {
    const int c = tid;
    const int cc = c & 127;
    const int rbase = (c < HID) ? 1 : 65;
#pragma unroll
    for (int p = 0; p < 8; ++p) {
      bf16x8 pk;
#pragma unroll
      for (int m = 0; m < 8; ++m)
        pk[m] = f2bf(W1[(rbase + p * 8 + m) * HID + cc]);
      *reinterpret_cast<bf16x8*>(wcat + c * 128 + ((p ^ (c & 7)) << 4)) = pk;
    }
  }
  if (blockIdx.x < 64) {
    const int e = blockIdx.x * 256 + tid;  // 0..16383
    const int kk = e >> 7, cc2 = e & 127;
    const int byo = cc2 * 256 + (((kk >> 3) ^ (cc2 & 7)) << 4) + (kk & 7) * 2;
    *reinterpret_cast<__hip_bfloat16*>(reinterpret_cast<char*>(w2swz) + byo) =
        __float2bfloat16(W2[kk * HID + cc2]);
  } else if (blockIdx.x == 64) {
    if (tid < HID) w0p[tid] = NEG_LOG2E * W1[tid];
    else b2p[tid - HID] = NEG_LOG2E * b2[tid - HID];
  }
  __syncthreads();

  const int wave = tid >> 6, lane = tid & 63;
  const int lr = lane & 15, kg = lane >> 4;
  const int r0 = blockIdx.x * 16;

  f32x4 acc[4];
#pragma unroll
  for (int ct = 0; ct < 4; ++ct) acc[ct] = {0.f, 0.f, 0.f, 0.f};

#pragma unroll
  for (int ks = 0; ks < 2; ++ks) {
    const float* fp = feat + (size_t)(r0 + lr) * F_IN + ks * 32 + kg * 8;
    const f32x4 fa = *reinterpret_cast<const f32x4*>(fp);
    const f32x4 fb = *reinterpret_cast<const f32x4*>(fp + 4);
    bf16x8 a;
#pragma unroll
    for (int m = 0; m < 4; ++m) {
      a[m] = f2bf(fa[m]);
      a[4 + m] = f2bf(fb[m]);
    }
    const int slot = ks * 4 + kg;
#pragma unroll
    for (int ct = 0; ct < 4; ++ct) {
      const int c = wave * 64 + ct * 16 + lr;
      const bf16x8 w = *reinterpret_cast<const bf16x8*>(
          wcat + c * 128 + ((slot ^ (c & 7)) << 4));
      acc[ct] = __builtin_amdgcn_mfma_f32_16x16x32_bf16(a, w, acc[ct], 0, 0, 0);
    }
  }
#pragma unroll
  for (int ct = 0; ct < 4; ++ct) {
    const int c = wave * 64 + ct * 16 + lr;
    const float badd = (c >= HID) ? b1[c - HID] : 0.f;
#pragma unroll
    for (int reg = 0; reg < 4; ++reg) {
      const int r = r0 + kg * 4 + reg;
      uvp[(size_t)r * 256 + c] = NEG_LOG2E * (acc[ct][reg] + badd);
    }
  }
}

// ---------------------------------------------------------------------------
// main: 4096 blocks = (b,i), 256 thr (4 waves). Wave owns 32 pair-rows x 128
// cols: acc[2][8] = 64 f32/lane. W2 (pre-swizzled) staged once in LDS; B-frags
// read per-ks in 2 batches of 4. z1 built in-register (one copy per pair),
// everything pre-scaled by -log2e: silu = z*rcp(1+exp2(z)), acc = -log2e*z2.
// Target: <=128 VGPR -> 4 waves/SIMD, 4 blocks/CU.
// ---------------------------------------------------------------------------
__global__ __launch_bounds__(256, 4) void sake_main(
    const float* __restrict__ coord,
    const float* __restrict__ w0p,
    const float* __restrict__ b2p,
    const float* __restrict__ uvp,
    const __hip_bfloat16* __restrict__ w2swz,
    float* __restrict__ part) {
  __shared__ __align__(16) char w2lds[HID * 256];  // 32 KB
  __shared__ float ssum[4][HID];

  const int tid = threadIdx.x;
  // XCD swizzle: 4096 -> 512 contiguous per XCD (4 graphs per XCD)
  const int bid = (blockIdx.x & 7) * 512 + (blockIdx.x >> 3);
  const int b = bid >> 7, i = bid & 127;

  // stage pre-swizzled W2 -> LDS (linear copy)
  {
    const char* src = reinterpret_cast<const char*>(w2swz);
#pragma unroll
    for (int p = 0; p < 8; ++p) {
      const int o = tid * 16 + p * 4096;
      *reinterpret_cast<int4*>(w2lds + o) =
          *reinterpret_cast<const int4*>(src + o);
    }
  }

  const int wave = tid >> 6, lane = tid & 63;
  const int lr = lane & 15, kg = lane >> 4;
  const int j0 = wave * 32;

  // d2 for rows j0+lr (t=0), j0+16+lr (t=1)  — exact f32
  const float* xi = coord + (size_t)(b * NN + i) * 3;
  const float xix = xi[0], xiy = xi[1], xiz = xi[2];
  float d2t[2];
#pragma unroll
  for (int t = 0; t < 2; ++t) {
    const float* xj = coord + (size_t)(b * NN + j0 + t * 16 + lr) * 3;
    const float dx = xj[0] - xix, dy = xj[1] - xiy, dz = xj[2] - xiz;
    d2t[t] = dx * dx + dy * dy + dz * dz;
  }

  // acc init = b2p[col], col = ct*16 + lr (broadcast over rows)
  f32x4 acc[2][8];
#pragma unroll
  for (int c = 0; c < 8; ++c) {
    const float bb = b2p[c * 16 + lr];
    acc[0][c] = {bb, bb, bb, bb};
    acc[1][c] = {bb, bb, bb, bb};
  }

  const float* vrow = uvp + ((size_t)b * NN + i) * 256 + HID;
  const float* u0 = uvp + ((size_t)b * NN + j0 + lr) * 256;
  const float* u1 = u0 + 16 * 256;

  __syncthreads();  // w2lds ready

#pragma unroll
  for (int ks = 0; ks < 4; ++ks) {
    const int c0 = ks * 32 + kg * 8;
    // z1' A-frags for both row-tiles (built in f32-quarters to cap live regs)
    bf16x8 zb[2];
#pragma unroll
    for (int t = 0; t < 2; ++t) {
      const float* up = (t ? u1 : u0) + c0;
#pragma unroll
      for (int h = 0; h < 2; ++h) {
        const f32x4 u4 = *reinterpret_cast<const f32x4*>(up + h * 4);
        const f32x4 v4 = *reinterpret_cast<const f32x4*>(vrow + c0 + h * 4);
        const f32x4 w4 = *reinterpret_cast<const f32x4*>(w0p + c0 + h * 4);
#pragma unroll
        for (int m = 0; m < 4; ++m) {
          const float z = fmaf(d2t[t], w4[m], u4[m] + v4[m]);
          zb[t][h * 4 + m] = f2bf(z * __builtin_amdgcn_rcpf(1.f + fexp2(z)));
        }
      }
    }
    // B-frags in 2 batches of 4 (16 transient VGPRs each)
    const int rbase = lr * 256 + ((((ks << 2) | kg) ^ (lr & 7)) << 4);
    bf16x8 wf[4];
#pragma unroll
    for (int c = 0; c < 4; ++c)
      wf[c] = *reinterpret_cast<const bf16x8*>(w2lds + rbase + c * 4096);
#pragma unroll
    for (int c = 0; c < 4; ++c) {
      acc[0][c] = __builtin_amdgcn_mfma_f32_16x16x32_bf16(zb[0], wf[c], acc[0][c], 0, 0, 0);
      acc[1][c] = __builtin_amdgcn_mfma_f32_16x16x32_bf16(zb[1], wf[c], acc[1][c], 0, 0, 0);
    }
#pragma unroll
    for (int c = 0; c < 4; ++c)
      wf[c] = *reinterpret_cast<const bf16x8*>(w2lds + rbase + (4 + c) * 4096);
#pragma unroll
    for (int c = 0; c < 4; ++c) {
      acc[0][4 + c] = __builtin_amdgcn_mfma_f32_16x16x32_bf16(zb[0], wf[c], acc[0][4 + c], 0, 0, 0);
      acc[1][4 + c] = __builtin_amdgcn_mfma_f32_16x16x32_bf16(zb[1], wf[c], acc[1][4 + c], 0, 0, 0);
    }
  }

  // z2 epilogue: acc = -log2e*z2; csum[c] = sum over this wave's 32 rows of
  // -log2e*silu(z2) for channel c*16+lr  (C-layout: col=lr, row=kg*4+m)
#pragma unroll
  for (int c = 0; c < 8; ++c) {
    float s = 0.f;
#pragma unroll
    for (int t = 0; t < 2; ++t)
#pragma unroll
      for (int m = 0; m < 4; ++m) {
        const float z = acc[t][c][m];
        s = fmaf(z, __builtin_amdgcn_rcpf(1.f + fexp2(z)), s);
      }
    s += __shfl_xor(s, 16);  // reduce across kg groups (rows)
    s += __shfl_xor(s, 32);
    acc[0][c][0] = s;  // stash
  }
  if (lane < 16) {
#pragma unroll
    for (int c = 0; c < 8; ++c) ssum[wave][c * 16 + lane] = acc[0][c][0];
  }
  __syncthreads();
  if (tid < HID) {
    part[(size_t)bid * HID + tid] =
        ssum[0][tid] + ssum[1][tid] + ssum[2][tid] + ssum[3][tid];
  }
}

// ---------------------------------------------------------------------------
// final: out[b] = -ln2*(sum_i part[b*128+i]) @ W3 + 16384*b3   (f32, exact)
// ---------------------------------------------------------------------------
__global__ void final_kernel(const float* __restrict__ part,
                             const float* __restrict__ W3,
                             const float* __restrict__ b3,
                             float* __restrict__ out) {
  __shared__ float s2[2][HID];
  __shared__ float s[HID];
  int b = blockIdx.x, t = threadIdx.x;
  int c = t & 127, half = t >> 7;
  float a = 0.f;
  for (int g = half * 64; g < half * 64 + 64; ++g)
    a += part[(size_t)(b * NN + g) * HID + c];
  s2[half][c] = a;
  __syncthreads();
  if (t < HID) s[t] = (s2[0][t] + s2[1][t]) * NEG_LN2;  // undo -log2e scale
  __syncthreads();
  if (t < OUTF) {
    float o = 16384.f * b3[t];
    for (int c2 = 0; c2 < HID; ++c2) o += s[c2] * W3[c2 * OUTF + t];
    out[b * OUTF + t] = o;
  }
}

// ---------------------------------------------------------------------------
extern "C" void kernel_launch(void* const* d_in, const int* in_sizes, int n_in,
                              void* d_out, int out_size, void* d_ws, size_t ws_size,
                              hipStream_t stream) {
  const float* feat = (const float*)d_in[0];
  const float* coord = (const float*)d_in[1];
  const float* W1 = (const float*)d_in[2];
  const float* b1 = (const float*)d_in[3];
  const float* W2 = (const float*)d_in[4];
  const float* b2 = (const float*)d_in[5];
  const float* W3 = (const float*)d_in[6];
  const float* b3 = (const float*)d_in[7];
  float* out = (float*)d_out;

  char* ws = (char*)d_ws;
  __hip_bfloat16* w2swz = (__hip_bfloat16*)ws;            // 32 KB (swizzled W2^T)
  float* w0p = (float*)(ws + 32 * 1024);                  // 512 B
  float* b2p = (float*)(ws + 36 * 1024);                  // 512 B
  float* uvp = (float*)(ws + 64 * 1024);                  // 4 MB
  float* part = (float*)(ws + 64 * 1024 + 4096 * 1024);   // 2 MB (4096 x 128)

  uv_prep<<<256, 256, 0, stream>>>(feat, W1, W2, b1, b2, uvp, w2swz, w0p, b2p);
  sake_main<<<TOTAL, 256, 0, stream>>>(coord, w0p, b2p, uvp, w2swz, part);
  final_kernel<<<NB, 256, 0, stream>>>(part, W3, b3, out);
}

// Round 9
// 60.215 us; speedup vs baseline: 3.2109x; 1.0045x over previous
//
#include <hip/hip_runtime.h>
#include <hip/hip_bf16.h>

// 32 graphs x 128 nodes, F=64, HID=128, OUT=64
#define F_IN 64
#define HID 128
#define OUTF 64
#define NN 128
#define NB 32
#define TOTAL 4096

#define NEG_LOG2E (-1.4426950408889634f)
#define NEG_LN2 (-0.6931471805599453f)

typedef short bf16x8 __attribute__((ext_vector_type(8)));
typedef float f32x4 __attribute__((ext_vector_type(4)));

static __device__ __forceinline__ short f2bf(float v) {
  __hip_bfloat16 h = __float2bfloat16(v);
  return __builtin_bit_cast(short, h);
}

static __device__ __forceinline__ float fexp2(float x) {
#if __has_builtin(__builtin_amdgcn_exp2f)
  return __builtin_amdgcn_exp2f(x);  // v_exp_f32 is natively 2^x
#else
  return exp2f(x);
#endif
}

// ---------------------------------------------------------------------------
// uv_prep: 256 blocks x 256 thr; block handles 16 nodes.  (r7-proven)
//   uvp[n][c] = -log2e * (h[n]@Wcat[:,c] + (c>=128 ? b1[c-128] : 0))
// Blocks 0-63 emit PRE-SWIZZLED bf16 W2^T (w2swz). Block 64 emits
// w0p=-log2e*W1[0,:], b2p=-log2e*b2.
// ---------------------------------------------------------------------------
__global__ __launch_bounds__(256) void uv_prep(
    const float* __restrict__ feat,
    const float* __restrict__ W1,
    const float* __restrict__ W2,
    const float* __restrict__ b1,
    const float* __restrict__ b2,
    float* __restrict__ uvp,
    __hip_bfloat16* __restrict__ w2swz,
    float* __restrict__ w0p,
    float* __restrict__ b2p) {
  __shared__ __align__(16) char wcat[256 * 128];  // 256 cols x 64 k bf16
  const int tid = threadIdx.x;
  {
    const int c = tid;
    const int cc = c & 127;
    const int rbase = (c < HID) ? 1 : 65;
#pragma unroll
    for (int p = 0; p < 8; ++p) {
      bf16x8 pk;
#pragma unroll
      for (int m = 0; m < 8; ++m)
        pk[m] = f2bf(W1[(rbase + p * 8 + m) * HID + cc]);
      *reinterpret_cast<bf16x8*>(wcat + c * 128 + ((p ^ (c & 7)) << 4)) = pk;
    }
  }
  if (blockIdx.x < 64) {
    const int e = blockIdx.x * 256 + tid;  // 0..16383
    const int kk = e >> 7, cc2 = e & 127;
    const int byo = cc2 * 256 + (((kk >> 3) ^ (cc2 & 7)) << 4) + (kk & 7) * 2;
    *reinterpret_cast<__hip_bfloat16*>(reinterpret_cast<char*>(w2swz) + byo) =
        __float2bfloat16(W2[kk * HID + cc2]);
  } else if (blockIdx.x == 64) {
    if (tid < HID) w0p[tid] = NEG_LOG2E * W1[tid];
    else b2p[tid - HID] = NEG_LOG2E * b2[tid - HID];
  }
  __syncthreads();

  const int wave = tid >> 6, lane = tid & 63;
  const int lr = lane & 15, kg = lane >> 4;
  const int r0 = blockIdx.x * 16;

  f32x4 acc[4];
#pragma unroll
  for (int ct = 0; ct < 4; ++ct) acc[ct] = {0.f, 0.f, 0.f, 0.f};

#pragma unroll
  for (int ks = 0; ks < 2; ++ks) {
    const float* fp = feat + (size_t)(r0 + lr) * F_IN + ks * 32 + kg * 8;
    const f32x4 fa = *reinterpret_cast<const f32x4*>(fp);
    const f32x4 fb = *reinterpret_cast<const f32x4*>(fp + 4);
    bf16x8 a;
#pragma unroll
    for (int m = 0; m < 4; ++m) {
      a[m] = f2bf(fa[m]);
      a[4 + m] = f2bf(fb[m]);
    }
    const int slot = ks * 4 + kg;
#pragma unroll
    for (int ct = 0; ct < 4; ++ct) {
      const int c = wave * 64 + ct * 16 + lr;
      const bf16x8 w = *reinterpret_cast<const bf16x8*>(
          wcat + c * 128 + ((slot ^ (c & 7)) << 4));
      acc[ct] = __builtin_amdgcn_mfma_f32_16x16x32_bf16(a, w, acc[ct], 0, 0, 0);
    }
  }
#pragma unroll
  for (int ct = 0; ct < 4; ++ct) {
    const int c = wave * 64 + ct * 16 + lr;
    const float badd = (c >= HID) ? b1[c - HID] : 0.f;
#pragma unroll
    for (int reg = 0; reg < 4; ++reg) {
      const int r = r0 + kg * 4 + reg;
      uvp[(size_t)r * 256 + c] = NEG_LOG2E * (acc[ct][reg] + badd);
    }
  }
}

// ---------------------------------------------------------------------------
// main: 4096 blocks = (b,i), 256 thr (4 waves). Wave owns 32 pair-rows x 128
// cols (acc[2][8]). u (the only L2-latency load in the loop) is rolling-
// prefetched one ks ahead in 16 named VGPRs per tile. W2 pre-swizzled in
// LDS; B-frags reused by both row-tiles. All values pre-scaled by -log2e:
// silu' = z*rcp(1+exp2(z)) = -log2e*silu(z); acc = -log2e*z2.
// __launch_bounds__(256,3): r7 measured ~35% occupancy anyway; spend the
// regs on the prefetch instead of declaring 4 waves we never got.
// ---------------------------------------------------------------------------
__global__ __launch_bounds__(256, 3) void sake_main(
    const float* __restrict__ coord,
    const float* __restrict__ w0p,
    const float* __restrict__ b2p,
    const float* __restrict__ uvp,
    const __hip_bfloat16* __restrict__ w2swz,
    float* __restrict__ part) {
  __shared__ __align__(16) char w2lds[HID * 256];  // 32 KB
  __shared__ float ssum[4][HID];

  const int tid = threadIdx.x;
  // XCD swizzle: 4096 -> 512 contiguous per XCD (4 graphs per XCD)
  const int bid = (blockIdx.x & 7) * 512 + (blockIdx.x >> 3);
  const int b = bid >> 7, i = bid & 127;

  // stage pre-swizzled W2 -> LDS (linear copy)
  {
    const char* src = reinterpret_cast<const char*>(w2swz);
#pragma unroll
    for (int p = 0; p < 8; ++p) {
      const int o = tid * 16 + p * 4096;
      *reinterpret_cast<int4*>(w2lds + o) =
          *reinterpret_cast<const int4*>(src + o);
    }
  }

  const int wave = tid >> 6, lane = tid & 63;
  const int lr = lane & 15, kg = lane >> 4;
  const int j0 = wave * 32;

  const float* urow0 = uvp + ((size_t)b * NN + j0 + lr) * 256;       // tile 0
  const float* urow1 = urow0 + 16 * 256;                             // tile 1
  const float* vrow = uvp + ((size_t)b * NN + i) * 256 + HID;

  // prefetch u for ks=0 (both tiles) BEFORE the barrier — global loads are
  // independent of the LDS stage
  f32x4 uA0 = *reinterpret_cast<const f32x4*>(urow0 + kg * 8);
  f32x4 uA1 = *reinterpret_cast<const f32x4*>(urow0 + kg * 8 + 4);
  f32x4 uA2 = *reinterpret_cast<const f32x4*>(urow1 + kg * 8);
  f32x4 uA3 = *reinterpret_cast<const f32x4*>(urow1 + kg * 8 + 4);

  // d2 for rows j0+lr (t=0), j0+16+lr (t=1) — exact f32
  const float* xi = coord + (size_t)(b * NN + i) * 3;
  const float xix = xi[0], xiy = xi[1], xiz = xi[2];
  float d2t[2];
#pragma unroll
  for (int t = 0; t < 2; ++t) {
    const float* xj = coord + (size_t)(b * NN + j0 + t * 16 + lr) * 3;
    const float dx = xj[0] - xix, dy = xj[1] - xiy, dz = xj[2] - xiz;
    d2t[t] = dx * dx + dy * dy + dz * dz;
  }

  // acc init = b2p[col], col = c*16 + lr (broadcast over rows)
  f32x4 acc[2][8];
#pragma unroll
  for (int c = 0; c < 8; ++c) {
    const float bb = b2p[c * 16 + lr];
    acc[0][c] = {bb, bb, bb, bb};
    acc[1][c] = {bb, bb, bb, bb};
  }

  __syncthreads();  // w2lds ready

#pragma unroll
  for (int ks = 0; ks < 4; ++ks) {
    // issue next-ks u loads NOW; latency hides under this ks's trans+MFMA
    f32x4 uB0, uB1, uB2, uB3;
    if (ks < 3) {
      const int cn = (ks + 1) * 32 + kg * 8;
      uB0 = *reinterpret_cast<const f32x4*>(urow0 + cn);
      uB1 = *reinterpret_cast<const f32x4*>(urow0 + cn + 4);
      uB2 = *reinterpret_cast<const f32x4*>(urow1 + cn);
      uB3 = *reinterpret_cast<const f32x4*>(urow1 + cn + 4);
    }
    const int c0 = ks * 32 + kg * 8;
    const f32x4 v0 = *reinterpret_cast<const f32x4*>(vrow + c0);
    const f32x4 v1 = *reinterpret_cast<const f32x4*>(vrow + c0 + 4);
    const f32x4 w0 = *reinterpret_cast<const f32x4*>(w0p + c0);
    const f32x4 w1 = *reinterpret_cast<const f32x4*>(w0p + c0 + 4);

    // z1' = -log2e*z1 ; s = z1'*rcp(1+2^z1') = -log2e*silu(z1)
    bf16x8 zb[2];
#pragma unroll
    for (int m = 0; m < 4; ++m) {
      const float z = fmaf(d2t[0], w0[m], uA0[m] + v0[m]);
      zb[0][m] = f2bf(z * __builtin_amdgcn_rcpf(1.f + fexp2(z)));
    }
#pragma unroll
    for (int m = 0; m < 4; ++m) {
      const float z = fmaf(d2t[0], w1[m], uA1[m] + v1[m]);
      zb[0][4 + m] = f2bf(z * __builtin_amdgcn_rcpf(1.f + fexp2(z)));
    }
#pragma unroll
    for (int m = 0; m < 4; ++m) {
      const float z = fmaf(d2t[1], w0[m], uA2[m] + v0[m]);
      zb[1][m] = f2bf(z * __builtin_amdgcn_rcpf(1.f + fexp2(z)));
    }
#pragma unroll
    for (int m = 0; m < 4; ++m) {
      const float z = fmaf(d2t[1], w1[m], uA3[m] + v1[m]);
      zb[1][4 + m] = f2bf(z * __builtin_amdgcn_rcpf(1.f + fexp2(z)));
    }

    // B-frags in 2 batches of 4 (16 transient VGPRs), reused by both tiles
    const int rbase = lr * 256 + ((((ks << 2) | kg) ^ (lr & 7)) << 4);
    bf16x8 wf[4];
#pragma unroll
    for (int c = 0; c < 4; ++c)
      wf[c] = *reinterpret_cast<const bf16x8*>(w2lds + rbase + c * 4096);
#pragma unroll
    for (int c = 0; c < 4; ++c) {
      acc[0][c] = __builtin_amdgcn_mfma_f32_16x16x32_bf16(zb[0], wf[c], acc[0][c], 0, 0, 0);
      acc[1][c] = __builtin_amdgcn_mfma_f32_16x16x32_bf16(zb[1], wf[c], acc[1][c], 0, 0, 0);
    }
#pragma unroll
    for (int c = 0; c < 4; ++c)
      wf[c] = *reinterpret_cast<const bf16x8*>(w2lds + rbase + (4 + c) * 4096);
#pragma unroll
    for (int c = 0; c < 4; ++c) {
      acc[0][4 + c] = __builtin_amdgcn_mfma_f32_16x16x32_bf16(zb[0], wf[c], acc[0][4 + c], 0, 0, 0);
      acc[1][4 + c] = __builtin_amdgcn_mfma_f32_16x16x32_bf16(zb[1], wf[c], acc[1][4 + c], 0, 0, 0);
    }

    uA0 = uB0; uA1 = uB1; uA2 = uB2; uA3 = uB3;
  }

  // z2 epilogue: acc = -log2e*z2; csum[c] = sum over this wave's 32 rows of
  // -log2e*silu(z2) for channel c*16+lr (C-layout: col=lr, row=kg*4+m)
#pragma unroll
  for (int c = 0; c < 8; ++c) {
    float s = 0.f;
#pragma unroll
    for (int t = 0; t < 2; ++t)
#pragma unroll
      for (int m = 0; m < 4; ++m) {
        const float z = acc[t][c][m];
        s = fmaf(z, __builtin_amdgcn_rcpf(1.f + fexp2(z)), s);
      }
    s += __shfl_xor(s, 16);  // reduce across kg groups (rows)
    s += __shfl_xor(s, 32);
    acc[0][c][0] = s;  // stash
  }
  if (lane < 16) {
#pragma unroll
    for (int c = 0; c < 8; ++c) ssum[wave][c * 16 + lane] = acc[0][c][0];
  }
  __syncthreads();
  if (tid < HID) {
    part[(size_t)bid * HID + tid] =
        ssum[0][tid] + ssum[1][tid] + ssum[2][tid] + ssum[3][tid];
  }
}

// ---------------------------------------------------------------------------
// final: out[b] = -ln2*(sum_i part[b*128+i]) @ W3 + 16384*b3   (f32, exact)
// ---------------------------------------------------------------------------
__global__ void final_kernel(const float* __restrict__ part,
                             const float* __restrict__ W3,
                             const float* __restrict__ b3,
                             float* __restrict__ out) {
  __shared__ float s2[2][HID];
  __shared__ float s[HID];
  int b = blockIdx.x, t = threadIdx.x;
  int c = t & 127, half = t >> 7;
  float a = 0.f;
  for (int g = half * 64; g < half * 64 + 64; ++g)
    a += part[(size_t)(b * NN + g) * HID + c];
  s2[half][c] = a;
  __syncthreads();
  if (t < HID) s[t] = (s2[0][t] + s2[1][t]) * NEG_LN2;  // undo -log2e scale
  __syncthreads();
  if (t < OUTF) {
    float o = 16384.f * b3[t];
    for (int c2 = 0; c2 < HID; ++c2) o += s[c2] * W3[c2 * OUTF + t];
    out[b * OUTF + t] = o;
  }
}

// ---------------------------------------------------------------------------
extern "C" void kernel_launch(void* const* d_in, const int* in_sizes, int n_in,
                              void* d_out, int out_size, void* d_ws, size_t ws_size,
                              hipStream_t stream) {
  const float* feat = (const float*)d_in[0];
  const float* coord = (const float*)d_in[1];
  const float* W1 = (const float*)d_in[2];
  const float* b1 = (const float*)d_in[3];
  const float* W2 = (const float*)d_in[4];
  const float* b2 = (const float*)d_in[5];
  const float* W3 = (const float*)d_in[6];
  const float* b3 = (const float*)d_in[7];
  float* out = (float*)d_out;

  // workspace layout (~6.2 MB — r7-proven budget)
  char* ws = (char*)d_ws;
  __hip_bfloat16* w2swz = (__hip_bfloat16*)ws;            // 32 KB (swizzled W2^T)
  float* w0p = (float*)(ws + 32 * 1024);                  // 512 B
  float* b2p = (float*)(ws + 36 * 1024);                  // 512 B
  float* uvp = (float*)(ws + 64 * 1024);                  // 4 MB
  float* part = (float*)(ws + 64 * 1024 + 4096 * 1024);   // 2 MB (4096 x 128)

  uv_prep<<<256, 256, 0, stream>>>(feat, W1, W2, b1, b2, uvp, w2swz, w0p, b2p);
  sake_main<<<TOTAL, 256, 0, stream>>>(coord, w0p, b2p, uvp, w2swz, part);
  final_kernel<<<NB, 256, 0, stream>>>(part, W3, b3, out);
}